// Round 1
// baseline (839.409 us; speedup 1.0000x reference)
//
#include <hip/hip_runtime.h>
#include <math.h>

#define IN_DIM 128
#define HID 64
#define OUTD 32

// ---------------- degree / norm ----------------

__global__ void k_init_deg(int* __restrict__ deg, int n) {
    int i = blockIdx.x * blockDim.x + threadIdx.x;
    if (i < n) deg[i] = 1;  // self-loop contributes 1
}

__global__ void k_scatter_deg(const int* __restrict__ dst, int* __restrict__ deg, int e) {
    int i = blockIdx.x * blockDim.x + threadIdx.x;
    if (i < e) atomicAdd(&deg[dst[i]], 1);
}

__global__ void k_dinv(const int* __restrict__ deg, float* __restrict__ dinv, int n) {
    int i = blockIdx.x * blockDim.x + threadIdx.x;
    if (i < n) dinv[i] = rsqrtf((float)deg[i]);
}

// ---------------- dense matmul: H[n,D] = X[n,K] @ W[K,D] ----------------
// blockDim = 256, NPB = 256/D nodes per block. Each thread computes one
// (node, out-feature). X rows staged in LDS (broadcast reads within each
// D-thread group); W reads are coalesced across f and L1/L2-cached.
template<int K, int D>
__global__ void k_matmul(const float* __restrict__ X, const float* __restrict__ W,
                         float* __restrict__ H, int n) {
    constexpr int NPB = 256 / D;
    __shared__ float xs[NPB][K];
    int node0 = blockIdx.x * NPB;
    int lid = threadIdx.x;
    for (int idx = lid; idx < NPB * K; idx += 256) {
        int nn = idx / K, kk = idx % K;
        int gn = node0 + nn;
        xs[nn][kk] = (gn < n) ? X[(size_t)gn * K + kk] : 0.0f;
    }
    __syncthreads();
    int g = lid / D, f = lid % D;
    int node = node0 + g;
    if (node >= n) return;
    float acc = 0.0f;
#pragma unroll
    for (int k = 0; k < K; ++k) acc = fmaf(xs[g][k], W[k * D + f], acc);
    H[(size_t)node * D + f] = acc;
}

// ---------------- aggregation ----------------
// Self-loop term also serves as full initialization of A (no memset needed).
template<int D>
__global__ void k_selfloop_init(const float* __restrict__ H, const float* __restrict__ dinv,
                                float* __restrict__ A, int n) {
    int t = blockIdx.x * blockDim.x + threadIdx.x;
    if (t >= n * D) return;
    int i = t / D;
    float dv = dinv[i];
    A[t] = H[t] * dv * dv;
}

template<int D>
__global__ void k_scatter_edges(const int* __restrict__ src, const int* __restrict__ dst,
                                const float* __restrict__ H, const float* __restrict__ dinv,
                                float* A, int e) {
    int t = blockIdx.x * blockDim.x + threadIdx.x;
    int ei = t / D, f = t % D;
    if (ei >= e) return;
    int s = src[ei], d = dst[ei];
    float w = dinv[s] * dinv[d];
    atomicAdd(&A[(size_t)d * D + f], H[(size_t)s * D + f] * w);
}

__global__ void k_relu_bias(float* __restrict__ A, const float* __restrict__ b, int n) {
    int t = blockIdx.x * blockDim.x + threadIdx.x;
    if (t < n * HID) A[t] = fmaxf(A[t] + b[t & (HID - 1)], 0.0f);
}

// ---------------- column z-score ----------------

__global__ void k_zero_stats(double* __restrict__ st) {
    int i = threadIdx.x;
    if (i < 64) st[i] = 0.0;
}

// st[0..31] = column sums, st[32..63] = column sum-of-squares
__global__ void k_stats(const float* __restrict__ O, double* __restrict__ st, int n) {
    int tid = threadIdx.x;
    int c = tid & 31;  // column is invariant under strides that are multiples of 32
    double s = 0.0, q = 0.0;
    long total = (long)n * OUTD;
    for (long t = (long)blockIdx.x * blockDim.x + tid; t < total;
         t += (long)gridDim.x * blockDim.x) {
        double v = (double)O[t];
        s += v; q += v * v;
    }
    __shared__ double ls[256], lq[256];
    ls[tid] = s; lq[tid] = q;
    __syncthreads();
    if (tid < 32) {
        for (int j = 32; j < 256; j += 32) { s += ls[tid + j]; q += lq[tid + j]; }
        atomicAdd(&st[c], s);
        atomicAdd(&st[c + 32], q);
    }
}

__global__ void k_finalize_stats(const double* __restrict__ st, float* __restrict__ mr, int n) {
    int c = threadIdx.x;
    if (c < 32) {
        double sum = st[c], sq = st[c + 32];
        double mean = sum / (double)n;
        double var = (sq - sum * sum / (double)n) / (double)(n - 1);
        mr[c] = (float)mean;
        mr[c + 32] = (float)(1.0 / sqrt(var));
    }
}

__global__ void k_transform(float* __restrict__ O, const float* __restrict__ mr, int n) {
    int t = blockIdx.x * blockDim.x + threadIdx.x;
    if (t < n * OUTD) {
        int c = t & 31;
        O[t] = (O[t] - mr[c]) * mr[c + 32];
    }
}

// ---------------- launch ----------------

extern "C" void kernel_launch(void* const* d_in, const int* in_sizes, int n_in,
                              void* d_out, int out_size, void* d_ws, size_t ws_size,
                              hipStream_t stream) {
    const float* x1 = (const float*)d_in[0];
    const int*   ei1 = (const int*)d_in[1];
    const float* x2 = (const float*)d_in[2];
    const int*   ei2 = (const int*)d_in[3];
    const float* W1 = (const float*)d_in[4];
    const float* b1 = (const float*)d_in[5];
    const float* W2 = (const float*)d_in[6];
    const float* b2 = (const float*)d_in[7];
    (void)b2;  // column-constant shift cancels exactly in the z-score
    (void)n_in; (void)out_size; (void)ws_size;

    int n = in_sizes[0] / IN_DIM;  // 50000
    int e = in_sizes[1] / 2;       // 800000
    float* out = (float*)d_out;

    char* ws = (char*)d_ws;
    size_t off = 0;
    auto alloc = [&](size_t bytes) {
        void* p = ws + off;
        off = (off + bytes + 255) & ~(size_t)255;
        return p;
    };
    float*  dinv = (float*)alloc((size_t)n * 4);
    int*    deg  = (int*)alloc((size_t)n * 4);
    float*  h    = (float*)alloc((size_t)n * HID * 4);
    float*  agg  = (float*)alloc((size_t)n * HID * 4);
    double* st   = (double*)alloc(64 * 8);
    float*  mr   = (float*)alloc(64 * 4);

    for (int g = 0; g < 2; ++g) {
        const float* x  = g ? x2 : x1;
        const int*   ei = g ? ei2 : ei1;
        const int* srcv = ei;       // edge_index[0]
        const int* dstv = ei + e;   // edge_index[1]
        float* og = out + (size_t)g * n * OUTD;

        k_init_deg<<<(n + 255) / 256, 256, 0, stream>>>(deg, n);
        k_scatter_deg<<<(e + 255) / 256, 256, 0, stream>>>(dstv, deg, e);
        k_dinv<<<(n + 255) / 256, 256, 0, stream>>>(deg, dinv, n);

        // layer 1
        k_matmul<IN_DIM, HID><<<(n + 3) / 4, 256, 0, stream>>>(x, W1, h, n);
        k_selfloop_init<HID><<<((size_t)n * HID + 255) / 256, 256, 0, stream>>>(h, dinv, agg, n);
        k_scatter_edges<HID><<<((size_t)e * HID + 255) / 256, 256, 0, stream>>>(srcv, dstv, h, dinv, agg, e);
        k_relu_bias<<<((size_t)n * HID + 255) / 256, 256, 0, stream>>>(agg, b1, n);

        // layer 2 (aggregate straight into the output slab)
        k_matmul<HID, OUTD><<<(n + 7) / 8, 256, 0, stream>>>(agg, W2, h, n);
        k_selfloop_init<OUTD><<<((size_t)n * OUTD + 255) / 256, 256, 0, stream>>>(h, dinv, og, n);
        k_scatter_edges<OUTD><<<((size_t)e * OUTD + 255) / 256, 256, 0, stream>>>(srcv, dstv, h, dinv, og, e);

        // z-score columns
        k_zero_stats<<<1, 64, 0, stream>>>(st);
        k_stats<<<1024, 256, 0, stream>>>(og, st, n);
        k_finalize_stats<<<1, 32, 0, stream>>>(st, mr, n);
        k_transform<<<((size_t)n * OUTD + 255) / 256, 256, 0, stream>>>(og, mr, n);
    }
}